// Round 6
// baseline (201.422 us; speedup 1.0000x reference)
//
#include <hip/hip_runtime.h>
#include <hip/hip_bf16.h>
#include <stdint.h>

// ---------------------------------------------------------------------------
// Net_75282186764473 — forward == 'experiment' dynamics (stop_grad identity).
// Euler algebra: p0=0 -> q1=q0 -> D1=D0 -> p2=2*D0 (exact); last step's p is
// discarded -> 3 MFMA phases per stage: D(q0), D(q2), D(q3).
// A = M'-fragments in registers (M' = dt*(c2q(W)+Qn-I); e folded as k=208 row
// driven by constant 1.0 in the sin buffer). Sin crosses waves via 3 LDS
// buffers (pow2 row stride + XOR-block swizzle). Batch=32 per block: two
// B-tiles per wave -> 8 independent MFMA chains (2x ILP vs R5), half the
// blocks, half the A-frag L2 traffic per unit work. 5 barriers per block.
// Output = fac * q[:,196:206]  (65536 x 10 fp32).
// ---------------------------------------------------------------------------

typedef __attribute__((ext_vector_type(8))) short bh8;
typedef __attribute__((ext_vector_type(4))) float f32x4;

#define TILES 13        // node tiles of 16 -> 208 (>= 206)
#define KSTEPS 7        // k tiles of 32 -> 224 (k=208 is the e-row)
#define ROWDW 128       // dwords per LDS sin row (pow2; XOR swizzle on 16B blks)
#define BROWS 32        // batch rows per block
#define BUFDW (BROWS * ROWDW)     // 4096 dwords per buffer

static __device__ __forceinline__ uint16_t bf16_bits(float v) {
    __hip_bfloat16 h = __float2bfloat16(v);
    return *reinterpret_cast<uint16_t*>(&h);
}

// diag[st*208+j] = -0.5*(colsum_j + rowsum_j) of C  (the c2q diagonal input)
__global__ void colrow_sums(const float* __restrict__ C1,
                            const float* __restrict__ C2,
                            float* __restrict__ d) {
    const float* C = blockIdx.x ? C2 : C1;
    const int N = blockIdx.x ? 206 : 196;
    const int j = threadIdx.x;             // 256 threads, j<N active
    if (j >= N) { if (j < 208) d[blockIdx.x * 208 + j] = 0.f; return; }
    float s = 0.f;
    for (int i = 0; i < N; ++i)
        s += C[i * N + j] + C[j * N + i];  // col (coalesced) + row (stream)
    d[blockIdx.x * 208 + j] = -0.5f * s;
}

// Pack A-frags of M' = dt*(c2q(C)+Qn-I), plus e-row at k==208:
// frag[((st*13+tile)*7+ks)*64+lane] = 8 bf16, elem j = M'[k][n],
//   k = ks*32+quad*8+j, n = tile*16+(lane&15).
__global__ void pack_frags(const float* __restrict__ C1, const float* __restrict__ Qn1,
                           const float* __restrict__ e1,
                           const float* __restrict__ C2, const float* __restrict__ Qn2,
                           const float* __restrict__ e2,
                           const float* __restrict__ diag,
                           uint16_t* __restrict__ frag) {
    const int bid = blockIdx.x;                 // 0..25
    const int st = bid / TILES, tile = bid % TILES;
    const float* C  = st ? C2 : C1;
    const float* Qn = st ? Qn2 : Qn1;
    const float* e  = st ? e2 : e1;
    const float* dd = diag + st * 208;
    const int N = st ? 206 : 196;
    const int t = threadIdx.x;                  // 256
    const int lane = t & 63, grp = t >> 6;
    const int quad = (lane >> 4) & 3;
    const int n = tile * 16 + (lane & 15);
    for (int ks = grp; ks < KSTEPS; ks += 4) {
        union { uint16_t v16[8]; uint4 v128; } vals;
        #pragma unroll
        for (int j = 0; j < 8; ++j) {
            const int k = ks * 32 + quad * 8 + j;
            float v = 0.f;
            if (n < N) {
                if (k < N) {
                    if (k == n) v = dd[n] + Qn[n * N + n] - 1.0f;
                    else        v = 0.5f * (C[k * N + n] + C[n * N + k]) + Qn[k * N + n];
                    v *= 0.1f;                  // fold dt
                } else if (k == 208) {
                    v = 0.1f * e[n];            // e-row (sin row 208 == 1.0)
                }
            }
            vals.v16[j] = bf16_bits(v);
        }
        const size_t off = ((size_t)(st * TILES + tile) * KSTEPS + ks) * 64 + lane;
        reinterpret_cast<uint4*>(frag)[off] = vals.v128;
    }
}

__global__ __launch_bounds__(256, 2) void pat_main(
    const float* __restrict__ x, const uint16_t* __restrict__ frag,
    const float* __restrict__ fac, float* __restrict__ out) {
    __shared__ __align__(16) uint32_t sinb[3 * BUFDW];    // 49,152 B
    const int tid = threadIdx.x;
    const int lane = tid & 63;
    const int w = __builtin_amdgcn_readfirstlane(tid >> 6);   // 0..3
    const int c = lane & 15, quad = lane >> 4;
    const uint32_t cs = (uint32_t)(c & 7);                    // XOR swizzle
    const long batch0 = (long)blockIdx.x * BROWS + c;         // bt=0 row; +16 for bt=1
    const int tiles[4] = {w, w + 4, w + 8, 12};
    const int ntiles = 3 + (w == 3);

    // zero all 3 buffers (covers pad rows k=209..223 and swizzle spill)
    {
        uint4 z; z.x = 0; z.y = 0; z.z = 0; z.w = 0;
        #pragma unroll
        for (int i = 0; i < 12; ++i)
            reinterpret_cast<uint4*>(sinb)[tid + i * 256] = z;
    }

    const bh8* fragv = reinterpret_cast<const bh8*>(frag);
    bh8 A[4][KSTEPS];
    #pragma unroll
    for (int nt = 0; nt < 4; ++nt)
        if (nt < ntiles)
            #pragma unroll
            for (int ks = 0; ks < KSTEPS; ++ks)
                A[nt][ks] = fragv[((size_t)tiles[nt] * KSTEPS + ks) * 64 + lane];

    float q[4][2][4];
    f32x4 P[4][2];
    #pragma unroll
    for (int nt = 0; nt < 4; ++nt) {
        const int n0 = tiles[nt] * 16 + quad * 4;
        #pragma unroll
        for (int bt = 0; bt < 2; ++bt) {
            const long batch = batch0 + bt * 16;
            if (nt < ntiles) {
                if (n0 + 3 < 196) {
                    const float4 v = *reinterpret_cast<const float4*>(x + batch * 196 + n0);
                    q[nt][bt][0] = v.x; q[nt][bt][1] = v.y;
                    q[nt][bt][2] = v.z; q[nt][bt][3] = v.w;
                } else {
                    #pragma unroll
                    for (int r = 0; r < 4; ++r)
                        q[nt][bt][r] = (n0 + r < 196) ? x[batch * 196 + n0 + r] : 0.f;
                }
            } else {
                #pragma unroll
                for (int r = 0; r < 4; ++r) q[nt][bt][r] = 0.f;
            }
            #pragma unroll
            for (int r = 0; r < 4; ++r) P[nt][bt][r] = 0.f;
        }
    }
    const float fout = fac[0];

    auto sin_phase = [&](int buf) {
        #pragma unroll
        for (int nt = 0; nt < 4; ++nt)
            if (nt < ntiles) {
                const uint32_t blk = ((uint32_t)(tiles[nt] * 2 + (quad >> 1))) ^ cs;
                #pragma unroll
                for (int bt = 0; bt < 2; ++bt) {
                    uint2 u;
                    u.x = (uint32_t)bf16_bits(__sinf(1.1f * q[nt][bt][0]))
                        | ((uint32_t)bf16_bits(__sinf(1.1f * q[nt][bt][1])) << 16);
                    u.y = (uint32_t)bf16_bits(__sinf(1.1f * q[nt][bt][2]))
                        | ((uint32_t)bf16_bits(__sinf(1.1f * q[nt][bt][3])) << 16);
                    *reinterpret_cast<uint2*>(
                        &sinb[buf * BUFDW + (c + bt * 16) * ROWDW
                              + blk * 4 + (quad & 1) * 2]) = u;
                }
            }
    };
    auto mfma_phase = [&](int buf) {
        #pragma unroll
        for (int ks = 0; ks < KSTEPS; ++ks) {
            const uint32_t koff = (((uint32_t)(ks * 4 + quad)) ^ cs) * 4;
            const bh8 b0 = *reinterpret_cast<const bh8*>(
                &sinb[buf * BUFDW + c * ROWDW + koff]);
            const bh8 b1 = *reinterpret_cast<const bh8*>(
                &sinb[buf * BUFDW + (c + 16) * ROWDW + koff]);
            #pragma unroll
            for (int nt = 0; nt < 4; ++nt)
                if (nt < ntiles) {
                    P[nt][0] = __builtin_amdgcn_mfma_f32_16x16x32_bf16(A[nt][ks], b0, P[nt][0], 0, 0, 0);
                    P[nt][1] = __builtin_amdgcn_mfma_f32_16x16x32_bf16(A[nt][ks], b1, P[nt][1], 0, 0, 0);
                }
        }
    };
    auto q_update = [&]() {
        #pragma unroll
        for (int nt = 0; nt < 4; ++nt)
            if (nt < ntiles)
                #pragma unroll
                for (int bt = 0; bt < 2; ++bt)
                    #pragma unroll
                    for (int r = 0; r < 4; ++r)
                        q[nt][bt][r] += 0.1f * P[nt][bt][r];
    };

    __syncthreads();                       // zeros visible
    // constant 1.0 at sin row k=208 (e-drive), all 3 buffers x 32 batch rows
    if (tid < 96) {
        const int bb = tid >> 5, cc = tid & 31;
        sinb[bb * BUFDW + cc * ROWDW + (26u ^ (uint32_t)(cc & 7)) * 4] = 0x3F80u;
    }
    sin_phase(0);                          // sin(q0) -> bufA
    __syncthreads();

    for (int stg = 0; stg < 2; ++stg) {
        mfma_phase(0);                     // P = D0  (p1)
        q_update();                        // q2 = q0 + 0.1*D0   (q1 == q0)
        sin_phase(1);                      // sin(q2) -> bufB
        #pragma unroll
        for (int nt = 0; nt < 4; ++nt)
            #pragma unroll
            for (int bt = 0; bt < 2; ++bt)
                #pragma unroll
                for (int r = 0; r < 4; ++r)
                    P[nt][bt][r] += P[nt][bt][r];               // p2 = 2*D0
        q_update();                        // q3
        sin_phase(2);                      // sin(q3) -> bufC
        __syncthreads();
        mfma_phase(1);                     // p3
        q_update();                        // q4
        mfma_phase(2);                     // p4
        if (stg == 0) {                    // prefetch stage-2 A into freed regs
            #pragma unroll
            for (int nt = 0; nt < 4; ++nt)
                if (nt < ntiles)
                    #pragma unroll
                    for (int ks = 0; ks < KSTEPS; ++ks)
                        A[nt][ks] = fragv[((size_t)(TILES + tiles[nt]) * KSTEPS + ks) * 64 + lane];
        }
        q_update();                        // q5 (stage-final q)
        if (stg == 0) {
            #pragma unroll
            for (int nt = 0; nt < 4; ++nt)
                #pragma unroll
                for (int bt = 0; bt < 2; ++bt)
                    #pragma unroll
                    for (int r = 0; r < 4; ++r) P[nt][bt][r] = 0.f;  // p resets
            sin_phase(0);                  // sin(q5) -> bufA for stage 2
            __syncthreads();
        }
    }

    // outputs: nodes 196..205 live in tile 12 (wave 3, nt=3)
    if (w == 3) {
        const int n0 = 192 + quad * 4;
        #pragma unroll
        for (int r = 0; r < 4; ++r) {
            const int node = n0 + r;
            if (node >= 196 && node < 206) {
                out[batch0 * 10 + (node - 196)]        = fout * q[3][0][r];
                out[(batch0 + 16) * 10 + (node - 196)] = fout * q[3][1][r];
            }
        }
    }
}

extern "C" void kernel_launch(void* const* d_in, const int* in_sizes, int n_in,
                              void* d_out, int out_size, void* d_ws, size_t ws_size,
                              hipStream_t stream) {
    const float* x   = (const float*)d_in[0];
    const float* w1  = (const float*)d_in[1];
    const float* b1  = (const float*)d_in[2];
    const float* w2  = (const float*)d_in[3];
    const float* b2  = (const float*)d_in[4];
    const float* fac = (const float*)d_in[5];
    const float* qn1 = (const float*)d_in[6];
    const float* qn2 = (const float*)d_in[7];
    float* out = (float*)d_out;

    float*    diag = (float*)d_ws;                        // 2*208 f32
    uint16_t* frg  = (uint16_t*)((char*)d_ws + 2048);     // 182 KB

    colrow_sums<<<2, 256, 0, stream>>>(w1, w2, diag);
    pack_frags<<<2 * TILES, 256, 0, stream>>>(w1, qn1, b1, w2, qn2, b2, diag, frg);

    const int B = in_sizes[0] / 196;       // 65536
    pat_main<<<B / BROWS, 256, 0, stream>>>(x, frg, fac, out);
}

// Round 7
// 135.181 us; speedup vs baseline: 1.4900x; 1.4900x over previous
//
#include <hip/hip_runtime.h>
#include <hip/hip_bf16.h>
#include <stdint.h>

// ---------------------------------------------------------------------------
// Net_75282186764473 — forward == 'experiment' dynamics (stop_grad identity).
// Euler algebra: p0=0 -> q1=q0 -> D1=D0 -> p2=2*D0 (exact); last step's p is
// discarded -> 3 MFMA phases per stage: D(q0), D(q2), D(q3).
// A = M'-fragments in registers (M' = dt*(c2q(W)+Qn-I); e folded as k=208 row
// driven by constant 1.0 in the sin buffer). Sin crosses waves via 3 LDS
// buffers (pow2 row stride + XOR-block swizzle). 512-thr blocks, 8 waves,
// <=2 node-tiles per wave (~110 VGPRs, no spills at the (512,4) 128-reg cap);
// batch=32/block -> 2 B-tiles per wave = 4 independent MFMA chains.
// Prep fully parallel: 416-block diag, 182-block pack. 5 barriers/block.
// Output = fac * q[:,196:206]  (65536 x 10 fp32).
// ---------------------------------------------------------------------------

typedef __attribute__((ext_vector_type(8))) short bh8;
typedef __attribute__((ext_vector_type(4))) float f32x4;

#define TILES 13        // node tiles of 16 -> 208 (>= 206)
#define KSTEPS 7        // k tiles of 32 -> 224 (k=208 is the e-row)
#define ROWDW 128       // dwords per LDS sin row (pow2; XOR swizzle on 16B blks)
#define BROWS 32        // batch rows per block
#define BUFDW (BROWS * ROWDW)     // 4096 dwords per buffer

static __device__ __forceinline__ uint16_t bf16_bits(float v) {
    __hip_bfloat16 h = __float2bfloat16(v);
    return *reinterpret_cast<uint16_t*>(&h);
}

// diag[st*208+j] = -sum_i 0.5*(C[i][j]+C[j][i])  — one wave per (stage,col)
__global__ void prep_diag(const float* __restrict__ C1,
                          const float* __restrict__ C2,
                          float* __restrict__ d) {
    const int bid = blockIdx.x;            // 0..415
    const int st = bid >> 8 ? 1 : (bid >= 208);   // st = bid/208
    const int j = bid - st * 208;
    const float* C = st ? C2 : C1;
    const int N = st ? 206 : 196;
    if (j >= N) return;
    const int t = threadIdx.x;             // 64
    float s = 0.f;
    for (int i = t; i < N; i += 64)
        s += 0.5f * (C[i * N + j] + C[j * N + i]);
    #pragma unroll
    for (int off = 32; off > 0; off >>= 1)
        s += __shfl_xor(s, off, 64);
    if (t == 0) d[st * 208 + j] = -s;
}

// Pack A-frags of M' = dt*(c2q(C)+Qn-I), plus e-row at k==208:
// frag[((st*13+tile)*7+ks)*64+lane] = 8 bf16, elem j = M'[k][n],
//   k = ks*32+quad*8+j, n = tile*16+(lane&15).  One wave per (st,tile,ks).
__global__ void pack_frags(const float* __restrict__ C1, const float* __restrict__ Qn1,
                           const float* __restrict__ e1,
                           const float* __restrict__ C2, const float* __restrict__ Qn2,
                           const float* __restrict__ e2,
                           const float* __restrict__ diag,
                           uint16_t* __restrict__ frag) {
    const int bid = blockIdx.x;                 // 0..181
    const int st = bid / (TILES * KSTEPS);
    const int rem = bid - st * (TILES * KSTEPS);
    const int tile = rem / KSTEPS, ks = rem % KSTEPS;
    const float* C  = st ? C2 : C1;
    const float* Qn = st ? Qn2 : Qn1;
    const float* e  = st ? e2 : e1;
    const float* dd = diag + st * 208;
    const int N = st ? 206 : 196;
    const int lane = threadIdx.x;               // 64
    const int quad = (lane >> 4) & 3;
    const int n = tile * 16 + (lane & 15);
    union { uint16_t v16[8]; uint4 v128; } vals;
    #pragma unroll
    for (int j = 0; j < 8; ++j) {
        const int k = ks * 32 + quad * 8 + j;
        float v = 0.f;
        if (n < N) {
            if (k < N) {
                if (k == n) v = dd[n] + Qn[n * N + n] - 1.0f;
                else        v = 0.5f * (C[k * N + n] + C[n * N + k]) + Qn[k * N + n];
                v *= 0.1f;                      // fold dt
            } else if (k == 208) {
                v = 0.1f * e[n];                // e-row (sin row 208 == 1.0)
            }
        }
        vals.v16[j] = bf16_bits(v);
    }
    const size_t off = ((size_t)(st * TILES + tile) * KSTEPS + ks) * 64 + lane;
    reinterpret_cast<uint4*>(frag)[off] = vals.v128;
}

__global__ __launch_bounds__(512, 4) void pat_main(
    const float* __restrict__ x, const uint16_t* __restrict__ frag,
    const float* __restrict__ fac, float* __restrict__ out) {
    __shared__ __align__(16) uint32_t sinb[3 * BUFDW];    // 49,152 B
    const int tid = threadIdx.x;
    const int lane = tid & 63;
    const int w = __builtin_amdgcn_readfirstlane(tid >> 6);   // 0..7
    const int c = lane & 15, quad = lane >> 4;
    const uint32_t cs = (uint32_t)(c & 7);                    // XOR swizzle
    const long batch0 = (long)blockIdx.x * BROWS + c;         // bt=0; +16 for bt=1
    // wave w<5 owns tiles {w, w+8}; waves 5..7 own {w}. Tile 12 -> wave 4.
    const int t0 = w, t1 = w + 8;
    const int ntiles = (w < 5) ? 2 : 1;

    // zero all 3 buffers (covers pad rows k=209..223 and swizzle spill)
    {
        uint4 z; z.x = 0; z.y = 0; z.z = 0; z.w = 0;
        #pragma unroll
        for (int i = 0; i < 6; ++i)
            reinterpret_cast<uint4*>(sinb)[tid + i * 512] = z;
    }

    const bh8* fragv = reinterpret_cast<const bh8*>(frag);
    bh8 A[2][KSTEPS];
    #pragma unroll
    for (int nt = 0; nt < 2; ++nt)
        if (nt < ntiles) {
            const int tile = nt ? t1 : t0;
            #pragma unroll
            for (int ks = 0; ks < KSTEPS; ++ks)
                A[nt][ks] = fragv[((size_t)tile * KSTEPS + ks) * 64 + lane];
        }

    float q[2][2][4];
    f32x4 P[2][2];
    #pragma unroll
    for (int nt = 0; nt < 2; ++nt) {
        const int n0 = (nt ? t1 : t0) * 16 + quad * 4;
        #pragma unroll
        for (int bt = 0; bt < 2; ++bt) {
            const long batch = batch0 + bt * 16;
            if (nt < ntiles && n0 + 3 < 196) {
                const float4 v = *reinterpret_cast<const float4*>(x + batch * 196 + n0);
                q[nt][bt][0] = v.x; q[nt][bt][1] = v.y;
                q[nt][bt][2] = v.z; q[nt][bt][3] = v.w;
            } else {
                #pragma unroll
                for (int r = 0; r < 4; ++r) q[nt][bt][r] = 0.f;
            }
            #pragma unroll
            for (int r = 0; r < 4; ++r) P[nt][bt][r] = 0.f;
        }
    }
    const float fout = fac[0];

    auto sin_phase = [&](int buf) {
        #pragma unroll
        for (int nt = 0; nt < 2; ++nt)
            if (nt < ntiles) {
                const int tile = nt ? t1 : t0;
                const uint32_t blk = ((uint32_t)(tile * 2 + (quad >> 1))) ^ cs;
                #pragma unroll
                for (int bt = 0; bt < 2; ++bt) {
                    uint2 u;
                    u.x = (uint32_t)bf16_bits(__sinf(1.1f * q[nt][bt][0]))
                        | ((uint32_t)bf16_bits(__sinf(1.1f * q[nt][bt][1])) << 16);
                    u.y = (uint32_t)bf16_bits(__sinf(1.1f * q[nt][bt][2]))
                        | ((uint32_t)bf16_bits(__sinf(1.1f * q[nt][bt][3])) << 16);
                    *reinterpret_cast<uint2*>(
                        &sinb[buf * BUFDW + (c + bt * 16) * ROWDW
                              + blk * 4 + (quad & 1) * 2]) = u;
                }
            }
    };
    auto mfma_phase = [&](int buf) {
        #pragma unroll
        for (int ks = 0; ks < KSTEPS; ++ks) {
            const uint32_t koff = (((uint32_t)(ks * 4 + quad)) ^ cs) * 4;
            const bh8 b0 = *reinterpret_cast<const bh8*>(
                &sinb[buf * BUFDW + c * ROWDW + koff]);
            const bh8 b1 = *reinterpret_cast<const bh8*>(
                &sinb[buf * BUFDW + (c + 16) * ROWDW + koff]);
            #pragma unroll
            for (int nt = 0; nt < 2; ++nt)
                if (nt < ntiles) {
                    P[nt][0] = __builtin_amdgcn_mfma_f32_16x16x32_bf16(A[nt][ks], b0, P[nt][0], 0, 0, 0);
                    P[nt][1] = __builtin_amdgcn_mfma_f32_16x16x32_bf16(A[nt][ks], b1, P[nt][1], 0, 0, 0);
                }
        }
    };
    auto q_update = [&]() {
        #pragma unroll
        for (int nt = 0; nt < 2; ++nt)
            if (nt < ntiles)
                #pragma unroll
                for (int bt = 0; bt < 2; ++bt)
                    #pragma unroll
                    for (int r = 0; r < 4; ++r)
                        q[nt][bt][r] += 0.1f * P[nt][bt][r];
    };

    __syncthreads();                       // zeros visible
    // constant 1.0 at sin element k=208 (e-drive), all 3 bufs x 32 batch rows
    if (tid < 96) {
        const int bb = tid >> 5, cc = tid & 31;
        sinb[bb * BUFDW + cc * ROWDW + (26u ^ (uint32_t)(cc & 7)) * 4] = 0x3F80u;
    }
    sin_phase(0);                          // sin(q0) -> bufA
    __syncthreads();

    for (int stg = 0; stg < 2; ++stg) {
        mfma_phase(0);                     // P = D0  (p1)
        q_update();                        // q2 = q0 + 0.1*D0   (q1 == q0)
        sin_phase(1);                      // sin(q2) -> bufB
        #pragma unroll
        for (int nt = 0; nt < 2; ++nt)
            #pragma unroll
            for (int bt = 0; bt < 2; ++bt)
                #pragma unroll
                for (int r = 0; r < 4; ++r)
                    P[nt][bt][r] += P[nt][bt][r];               // p2 = 2*D0
        q_update();                        // q3
        sin_phase(2);                      // sin(q3) -> bufC
        __syncthreads();
        mfma_phase(1);                     // p3
        q_update();                        // q4
        mfma_phase(2);                     // p4
        if (stg == 0) {                    // prefetch stage-2 A into freed regs
            #pragma unroll
            for (int nt = 0; nt < 2; ++nt)
                if (nt < ntiles) {
                    const int tile = nt ? t1 : t0;
                    #pragma unroll
                    for (int ks = 0; ks < KSTEPS; ++ks)
                        A[nt][ks] = fragv[((size_t)(TILES + tile) * KSTEPS + ks) * 64 + lane];
                }
        }
        q_update();                        // q5 (stage-final q)
        if (stg == 0) {
            #pragma unroll
            for (int nt = 0; nt < 2; ++nt)
                #pragma unroll
                for (int bt = 0; bt < 2; ++bt)
                    #pragma unroll
                    for (int r = 0; r < 4; ++r) P[nt][bt][r] = 0.f;  // p resets
            sin_phase(0);                  // sin(q5) -> bufA for stage 2
            __syncthreads();
        }
    }

    // outputs: nodes 196..205 live in tile 12 = wave 4's nt=1
    if (w == 4) {
        const int n0 = 192 + quad * 4;
        #pragma unroll
        for (int r = 0; r < 4; ++r) {
            const int node = n0 + r;
            if (node >= 196 && node < 206) {
                out[batch0 * 10 + (node - 196)]        = fout * q[1][0][r];
                out[(batch0 + 16) * 10 + (node - 196)] = fout * q[1][1][r];
            }
        }
    }
}

extern "C" void kernel_launch(void* const* d_in, const int* in_sizes, int n_in,
                              void* d_out, int out_size, void* d_ws, size_t ws_size,
                              hipStream_t stream) {
    const float* x   = (const float*)d_in[0];
    const float* w1  = (const float*)d_in[1];
    const float* b1  = (const float*)d_in[2];
    const float* w2  = (const float*)d_in[3];
    const float* b2  = (const float*)d_in[4];
    const float* fac = (const float*)d_in[5];
    const float* qn1 = (const float*)d_in[6];
    const float* qn2 = (const float*)d_in[7];
    float* out = (float*)d_out;

    float*    diag = (float*)d_ws;                        // 2*208 f32
    uint16_t* frg  = (uint16_t*)((char*)d_ws + 2048);     // 182 KB

    prep_diag<<<416, 64, 0, stream>>>(w1, w2, diag);
    pack_frags<<<2 * TILES * KSTEPS, 64, 0, stream>>>(w1, qn1, b1, w2, qn2, b2, diag, frg);

    const int B = in_sizes[0] / 196;       // 65536
    pat_main<<<B / BROWS, 512, 0, stream>>>(x, frg, fac, out);
}